// Round 15
// baseline (41.443 us; speedup 1.0000x reference)
//
#include <hip/hip_runtime.h>

#define BS 4
#define NQ 100
#define NT 25
#define NC 81
#define PIX 65536
#define KCHUNK 512
#define NKB (PIX / KCHUNK)       // 128 chunks per batch
#define STRY 520                 // LDS y row stride in ushorts (1040 B)
#define SLOT 216                 // u32 per slot: 200 packed-bf16-pairs + 16 f32 sp|sg

// ws layout (u32 units): two partial arrays, no atomics, no zero-init needed
#define PSZ   (BS * 8 * NKB * SLOT)      // 884,736 u32
#define WS_P1 PSZ                        // second array offset

typedef __attribute__((ext_vector_type(8))) short bf16x8;
typedef __attribute__((ext_vector_type(4))) float f32x4;

__device__ __forceinline__ float4 ld4(const float* p) {
    return *reinterpret_cast<const float4*>(p);
}
__device__ __forceinline__ f32x4 mfma16(bf16x8 a, bf16x8 b, f32x4 c) {
    return __builtin_amdgcn_mfma_f32_16x16x32_bf16(a, b, c, 0, 0, 0);
}
// truncation pack: two f32 -> two bf16 in one u32 (1 op)
__device__ __forceinline__ unsigned pack2t(float lo, float hi) {
#if __has_builtin(__builtin_amdgcn_perm)
    return __builtin_amdgcn_perm(__float_as_uint(hi), __float_as_uint(lo), 0x07060302u);
#else
    return (__float_as_uint(hi) & 0xFFFF0000u) | (__float_as_uint(lo) >> 16);
#endif
}
// round-half-up pack
__device__ __forceinline__ unsigned pack2r(float lo, float hi) {
#if __has_builtin(__builtin_amdgcn_perm)
    return __builtin_amdgcn_perm(__float_as_uint(hi) + 0x8000u,
                                 __float_as_uint(lo) + 0x8000u, 0x07060302u);
#else
    return (((__float_as_uint(hi) + 0x8000u) & 0xFFFF0000u) |
            ((__float_as_uint(lo) + 0x8000u) >> 16));
#endif
}
__device__ __forceinline__ float bflo(unsigned w) { return __uint_as_float(w << 16); }
__device__ __forceinline__ float bfhi(unsigned w) { return __uint_as_float(w & 0xFFFF0000u); }

union frag_u { unsigned u[4]; bf16x8 v; };

__global__ __launch_bounds__(256) void partial_kernel(
    const float* __restrict__ pm,   // [BS,NQ,PIX] mask logits
    const float* __restrict__ tm,   // [BS,NT,PIX] target masks
    unsigned* __restrict__ ws)
{
    // 25 real rows; by1 lanes with lrow>=9 read a clamped row (their MFMA
    // columns t=25..31 are discarded at the C-store).
    __shared__ unsigned short ys[NT * STRY];   // 26.0 KB

    const int tid = threadIdx.x;
    const int bid = blockIdx.x;
    const int chunk = bid & (NKB - 1);
    const int rest = bid >> 7;       // 0..7
    const int qg = rest & 1;
    const int b = rest >> 1;
    const int kbase = chunk * KCHUNK;

    // ---- stage y chunk (25 rows) as bf16 ----
    {
        const float* yg = tm + (size_t)b * NT * PIX + kbase;
        for (int j = tid; j < NT * (KCHUNK / 4); j += 256) {
            const int row = j >> 7, c = j & 127;
            const float4 v = ld4(yg + (size_t)row * PIX + c * 4);
            uint2 w;
            w.x = pack2r(v.x, v.y);
            w.y = pack2r(v.z, v.w);
            *reinterpret_cast<uint2*>(&ys[row * STRY + c * 4]) = w;
        }
    }
    __syncthreads();

    const int l = tid & 63;
    const int wv = tid >> 6;
    const int qt = qg * 4 + wv;              // 0..7
    const bool ones_wave = (qt == 7);        // all q invalid -> Sum(y) duty
    const int lrow = l & 15;
    const int lk = (l >> 4) * 8;             // px offset of this lane's 8 elements
    const int r1 = (lrow < NT - 16) ? (16 + lrow) : lrow;   // clamped by1 row

    const int q = qt * 16 + lrow;
    const bool qv = (q < NQ);

    const float* xp = pm + (size_t)(b * NQ + (qv ? q : 0)) * PIX + kbase + lk;

    f32x4 cxy[2] = {};
    f32x4 csy[2] = {};
    float sx = 0.f, sg = 0.f, l2 = 0.f;

    frag_u fones;
    fones.u[0] = fones.u[1] = fones.u[2] = fones.u[3] = 0x3F803F80u;  // bf16 1.0 x2

    // ---- 2-deep x prefetch ring ----
    float4 Xa[2], Xb[2];
    if (!ones_wave) {
        Xa[0] = ld4(xp);      Xb[0] = ld4(xp + 4);
        Xa[1] = ld4(xp + 32); Xb[1] = ld4(xp + 36);
    }

    // ---- LDS y-frag prefetch, 1 k-step ahead ----
    bf16x8 by0 = *reinterpret_cast<const bf16x8*>(&ys[lrow * STRY + lk]);
    bf16x8 by1 = *reinterpret_cast<const bf16x8*>(&ys[r1 * STRY + lk]);

    #pragma unroll
    for (int kb = 0; kb < KCHUNK / 32; ++kb) {
        bf16x8 nb0, nb1;
        if (kb < KCHUNK / 32 - 1) {
            const int ko = (kb + 1) * 32;
            nb0 = *reinterpret_cast<const bf16x8*>(&ys[lrow * STRY + ko + lk]);
            nb1 = *reinterpret_cast<const bf16x8*>(&ys[r1 * STRY + ko + lk]);
        }

        frag_u fx, fs;
        if (!ones_wave) {
            const float4 xa = Xa[kb & 1], xb = Xb[kb & 1];
            if (kb < KCHUNK / 32 - 2) {
                const int ko = (kb + 2) * 32;
                Xa[kb & 1] = ld4(xp + ko);
                Xb[kb & 1] = ld4(xp + ko + 4);
            }
            // r = sigmoid(x) = 1/(1+e^{-x})
            // sum softplus = sum x - ln2 * log2(prod r)   (one log per 8 elems)
            const float xe[8] = {xa.x, xa.y, xa.z, xa.w, xb.x, xb.y, xb.z, xb.w};
            float rg[8];
            float pr = 1.0f;
            #pragma unroll
            for (int e = 0; e < 8; ++e) {
                const float x = xe[e];
                const float ex = __expf(-x);
                const float r = __builtin_amdgcn_rcpf(1.0f + ex);
                rg[e] = r;
                pr *= r;          // prod of 8 sigmoids: >= ~1e-35 for |x|<~10
                sx += x;
                sg += r;          // garbage on invalid-q lanes lands in unread slots
            }
            l2 += __log2f(pr);
            #pragma unroll
            for (int e = 0; e < 4; ++e) {
                fx.u[e] = pack2t(xe[2 * e], xe[2 * e + 1]);
                fs.u[e] = pack2t(rg[2 * e], rg[2 * e + 1]);
            }
        } else {
            fx = fones; fs = fones;
        }

        cxy[0] = mfma16(fx.v, by0, cxy[0]);
        cxy[1] = mfma16(fx.v, by1, cxy[1]);
        csy[0] = mfma16(fs.v, by0, csy[0]);
        csy[1] = mfma16(fs.v, by1, csy[1]);

        if (kb < KCHUNK / 32 - 1) { by0 = nb0; by1 = nb1; }
    }

    if (!ones_wave) {
        // ---- C partials packed bf16x2 + f32 row sums -> plain stores ----
        const size_t slot = ((size_t)(b * 8 + qt) * NKB + chunk) * SLOT;
        unsigned* px = ws + slot;
        unsigned* ps = ws + WS_P1 + slot;
        #pragma unroll
        for (int n = 0; n < 2; ++n) {
            const int t = n * 16 + lrow;
            if (t < NT) {
                #pragma unroll
                for (int rp = 0; rp < 2; ++rp) {
                    const int qpair = (l >> 4) * 2 + rp;     // q-row pair index
                    px[t * 8 + qpair] = pack2r(cxy[n][2 * rp], cxy[n][2 * rp + 1]);
                    ps[t * 8 + qpair] = pack2r(csy[n][2 * rp], csy[n][2 * rp + 1]);
                }
            }
        }
        // row sums: lanes {l, l+16, l+32, l+48} share one q-row
        sx += __shfl_xor(sx, 16); sx += __shfl_xor(sx, 32);
        l2 += __shfl_xor(l2, 16); l2 += __shfl_xor(l2, 32);
        sg += __shfl_xor(sg, 16); sg += __shfl_xor(sg, 32);
        if (l < 16) {
            reinterpret_cast<float*>(px)[200 + l] = sx - 0.69314718056f * l2;
            reinterpret_cast<float*>(ps)[200 + l] = sg;
        }
    } else {
        // A == ones -> every C row = sum_k y[t]; f32 Sum(y) in qt=7 slot
        const size_t slot7 = ((size_t)(b * 8 + 7) * NKB + chunk) * SLOT;
        float* p7 = reinterpret_cast<float*>(ws + slot7);
        if (l < 16) p7[l] = cxy[0][0];
        if (l < NT - 16) p7[16 + l] = cxy[1][0];
    }
}

__global__ __launch_bounds__(256) void finalize_kernel(
    const float* __restrict__ logits,  // [BS,NQ,NC]
    const int* __restrict__ labels,    // [BS,NT]
    const unsigned* __restrict__ ws,
    float* __restrict__ out)           // [BS,NQ,NT]
{
    __shared__ float s1[256];
    __shared__ float s2[256];
    __shared__ float s3[256];
    __shared__ float s4[256];

    const int row = blockIdx.x;        // b*NQ + q
    const int b = row / NQ, q = row % NQ;
    const int qt = q / 16, qr = q % 16;
    const int tid = threadIdx.x;
    const int t = tid & 31, cg = tid >> 5;     // 8 chunk-groups

    const unsigned* px = ws + (size_t)(b * 8 + qt) * NKB * SLOT;
    const unsigned* ps = ws + WS_P1 + (size_t)(b * 8 + qt) * NKB * SLOT;
    const float* p7 = reinterpret_cast<const float*>(ws + (size_t)(b * 8 + 7) * NKB * SLOT);

    const int qpair = qr >> 1;
    const bool hi = (qr & 1);

    float a1 = 0.f, a2 = 0.f, a3 = 0.f, a4 = 0.f;
    if (t < NT) {
        #pragma unroll 4
        for (int k = 0; k < NKB / 8; ++k) {
            const size_t o = (size_t)(cg + 8 * k) * SLOT;
            const unsigned w1 = px[o + t * 8 + qpair];
            const unsigned w2 = ps[o + t * 8 + qpair];
            a1 += hi ? bfhi(w1) : bflo(w1);    // xy partial
            a2 += hi ? bfhi(w2) : bflo(w2);    // sy partial
            a3 += p7[o + t];                   // Sum_y partial (f32)
        }
    } else if (t == 25) {
        #pragma unroll 4
        for (int k = 0; k < NKB / 8; ++k)
            a4 += reinterpret_cast<const float*>(px)[(size_t)(cg + 8 * k) * SLOT + 200 + qr];
    } else if (t == 26) {
        #pragma unroll 4
        for (int k = 0; k < NKB / 8; ++k)
            a4 += reinterpret_cast<const float*>(ps)[(size_t)(cg + 8 * k) * SLOT + 200 + qr];
    }
    s1[tid] = a1;
    s2[tid] = a2;
    s3[tid] = a3;
    s4[tid] = a4;
    __syncthreads();

    if (tid < 64) {
        const float* lg = logits + (size_t)row * NC;
        float v0 = (tid < NC) ? lg[tid] : -1e30f;
        float v1 = (tid + 64 < NC) ? lg[tid + 64] : -1e30f;
        float mx = fmaxf(v0, v1);
        #pragma unroll
        for (int off = 32; off; off >>= 1) mx = fmaxf(mx, __shfl_xor(mx, off, 64));
        float e = ((tid < NC) ? __expf(v0 - mx) : 0.f) +
                  ((tid + 64 < NC) ? __expf(v1 - mx) : 0.f);
        #pragma unroll
        for (int off = 32; off; off >>= 1) e += __shfl_xor(e, off, 64);

        if (tid < NT) {
            float xy = 0.f, sy = 0.f, yt = 0.f, sp = 0.f, sgs = 0.f;
            #pragma unroll
            for (int g = 0; g < 8; ++g) {
                xy += s1[g * 32 + tid];
                sy += s2[g * 32 + tid];
                yt += s3[g * 32 + tid];
                sp += s4[g * 32 + 25];
                sgs += s4[g * 32 + 26];
            }

            const int lab = labels[b * NT + tid];
            const float prob = __expf(lg[lab] - mx) / e;
            const float inv_p = 1.0f / (float)PIX;
            const float bce = sp * inv_p - xy * inv_p;
            const float dice = 1.0f - 2.0f * sy / (sgs + yt + 1e-6f);
            out[(size_t)row * NT + tid] = -prob + bce + dice;
        }
    }
}

extern "C" void kernel_launch(void* const* d_in, const int* in_sizes, int n_in,
                              void* d_out, int out_size, void* d_ws, size_t ws_size,
                              hipStream_t stream) {
    const float* pred_logits = (const float*)d_in[0];
    const float* pred_masks  = (const float*)d_in[1];
    const int*   tgt_labels  = (const int*)d_in[2];
    const float* tgt_masks   = (const float*)d_in[3];
    float* out = (float*)d_out;
    unsigned* ws = (unsigned*)d_ws;

    // No memset, no atomics: every location finalize reads is unconditionally
    // overwritten by partial_kernel each call.
    partial_kernel<<<BS * 2 * NKB, 256, 0, stream>>>(pred_masks, tgt_masks, ws);
    finalize_kernel<<<BS * NQ, 256, 0, stream>>>(pred_logits, tgt_labels, ws, out);
}

// Round 16
// 38.944 us; speedup vs baseline: 1.0642x; 1.0642x over previous
//
#include <hip/hip_runtime.h>

#define BS 4
#define NQ 100
#define NT 25
#define NC 81
#define PIX 65536
#define KCHUNK 512
#define NKB (PIX / KCHUNK)       // 128 chunks per batch
#define STRY 520                 // LDS y row stride in ushorts (1040 B)
#define SLOT 432                 // per-(b,qt,chunk) slot: 400 xy|sy + 16 sp|sg + pad

// ws layout (floats): two partial arrays, no atomics, no zero-init needed
#define PSZ   (BS * 8 * NKB * SLOT)      // 1,769,472 floats
#define WS_P0 0                          // xy partials (+sp at 400; qt=7 slot: Sum_y at 0..25)
#define WS_P1 PSZ                        // sy partials (+sg at 400)

typedef __attribute__((ext_vector_type(8))) short bf16x8;
typedef __attribute__((ext_vector_type(4))) float f32x4;

__device__ __forceinline__ float4 ld4(const float* p) {
    return *reinterpret_cast<const float4*>(p);
}
__device__ __forceinline__ f32x4 mfma16(bf16x8 a, bf16x8 b, f32x4 c) {
    return __builtin_amdgcn_mfma_f32_16x16x32_bf16(a, b, c, 0, 0, 0);
}
// truncation pack: two f32 -> two bf16 in one u32 (1 op)
__device__ __forceinline__ unsigned pack2t(float lo, float hi) {
#if __has_builtin(__builtin_amdgcn_perm)
    return __builtin_amdgcn_perm(__float_as_uint(hi), __float_as_uint(lo), 0x07060302u);
#else
    return (__float_as_uint(hi) & 0xFFFF0000u) | (__float_as_uint(lo) >> 16);
#endif
}
// round-half-up pack (y staging only)
__device__ __forceinline__ unsigned pack2r(float lo, float hi) {
#if __has_builtin(__builtin_amdgcn_perm)
    return __builtin_amdgcn_perm(__float_as_uint(hi) + 0x8000u,
                                 __float_as_uint(lo) + 0x8000u, 0x07060302u);
#else
    return (((__float_as_uint(hi) + 0x8000u) & 0xFFFF0000u) |
            ((__float_as_uint(lo) + 0x8000u) >> 16));
#endif
}

union frag_u { unsigned u[4]; bf16x8 v; };

__global__ __launch_bounds__(256) void partial_kernel(
    const float* __restrict__ pm,   // [BS,NQ,PIX] mask logits
    const float* __restrict__ tm,   // [BS,NT,PIX] target masks
    float* __restrict__ ws)
{
    // 25 real rows; by1 lanes with lrow>=9 read a clamped row (their MFMA
    // columns t=25..31 are discarded at the C-store).
    __shared__ unsigned short ys[NT * STRY];   // 26.0 KB

    const int tid = threadIdx.x;
    const int bid = blockIdx.x;
    const int chunk = bid & (NKB - 1);
    const int rest = bid >> 7;       // 0..7
    const int qg = rest & 1;
    const int b = rest >> 1;
    const int kbase = chunk * KCHUNK;

    // ---- stage y chunk (25 rows) as bf16 ----
    {
        const float* yg = tm + (size_t)b * NT * PIX + kbase;
        for (int j = tid; j < NT * (KCHUNK / 4); j += 256) {
            const int row = j >> 7, c = j & 127;
            const float4 v = ld4(yg + (size_t)row * PIX + c * 4);
            uint2 w;
            w.x = pack2r(v.x, v.y);
            w.y = pack2r(v.z, v.w);
            *reinterpret_cast<uint2*>(&ys[row * STRY + c * 4]) = w;
        }
    }
    __syncthreads();

    const int l = tid & 63;
    const int wv = tid >> 6;
    const int qt = qg * 4 + wv;              // 0..7
    const bool ones_wave = (qt == 7);        // all q invalid -> Sum(y) duty
    const int lrow = l & 15;
    const int lk = (l >> 4) * 8;             // px offset of this lane's 8 elements
    const int r1 = (lrow < NT - 16) ? (16 + lrow) : lrow;   // clamped by1 row

    const int q = qt * 16 + lrow;
    const bool qv = (q < NQ);

    const float* xp = pm + (size_t)(b * NQ + (qv ? q : 0)) * PIX + kbase + lk;

    f32x4 cxy[2] = {};
    f32x4 csy[2] = {};
    float sx = 0.f, sg = 0.f, l2 = 0.f;

    frag_u fones;
    fones.u[0] = fones.u[1] = fones.u[2] = fones.u[3] = 0x3F803F80u;  // bf16 1.0 x2

    // ---- 2-deep x prefetch ring ----
    float4 Xa[2], Xb[2];
    if (!ones_wave) {
        Xa[0] = ld4(xp);      Xb[0] = ld4(xp + 4);
        Xa[1] = ld4(xp + 32); Xb[1] = ld4(xp + 36);
    }

    // ---- LDS y-frag prefetch, 1 k-step ahead ----
    bf16x8 by0 = *reinterpret_cast<const bf16x8*>(&ys[lrow * STRY + lk]);
    bf16x8 by1 = *reinterpret_cast<const bf16x8*>(&ys[r1 * STRY + lk]);

    #pragma unroll
    for (int kb = 0; kb < KCHUNK / 32; ++kb) {
        bf16x8 nb0, nb1;
        if (kb < KCHUNK / 32 - 1) {
            const int ko = (kb + 1) * 32;
            nb0 = *reinterpret_cast<const bf16x8*>(&ys[lrow * STRY + ko + lk]);
            nb1 = *reinterpret_cast<const bf16x8*>(&ys[r1 * STRY + ko + lk]);
        }

        frag_u fx, fs;
        if (!ones_wave) {
            const float4 xa = Xa[kb & 1], xb = Xb[kb & 1];
            if (kb < KCHUNK / 32 - 2) {
                const int ko = (kb + 2) * 32;
                Xa[kb & 1] = ld4(xp + ko);
                Xb[kb & 1] = ld4(xp + ko + 4);
            }
            // r = sigmoid(x) = 1/(1+e^{-x})
            // sum softplus = sum x - ln2 * log2(prod r)   (one log per 8 elems)
            const float xe[8] = {xa.x, xa.y, xa.z, xa.w, xb.x, xb.y, xb.z, xb.w};
            float rg[8];
            float pr = 1.0f;
            #pragma unroll
            for (int e = 0; e < 8; ++e) {
                const float x = xe[e];
                const float ex = __expf(-x);
                const float r = __builtin_amdgcn_rcpf(1.0f + ex);
                rg[e] = r;
                pr *= r;          // prod of 8 sigmoids: >= ~1e-35 for |x|<~10
                sx += x;
                sg += r;          // garbage on invalid-q lanes lands in unread slots
            }
            l2 += __log2f(pr);
            #pragma unroll
            for (int e = 0; e < 4; ++e) {
                fx.u[e] = pack2t(xe[2 * e], xe[2 * e + 1]);
                fs.u[e] = pack2t(rg[2 * e], rg[2 * e + 1]);
            }
        } else {
            fx = fones; fs = fones;
        }

        cxy[0] = mfma16(fx.v, by0, cxy[0]);
        cxy[1] = mfma16(fx.v, by1, cxy[1]);
        csy[0] = mfma16(fs.v, by0, csy[0]);
        csy[1] = mfma16(fs.v, by1, csy[1]);

        if (kb < KCHUNK / 32 - 1) { by0 = nb0; by1 = nb1; }
    }

    if (!ones_wave) {
        // ---- C partials + row sums -> plain stores, no atomics ----
        const size_t slot = ((size_t)(b * 8 + qt) * NKB + chunk) * SLOT;
        float* px = ws + WS_P0 + slot;
        float* ps = ws + WS_P1 + slot;
        #pragma unroll
        for (int n = 0; n < 2; ++n) {
            const int t = n * 16 + lrow;
            if (t < NT) {
                #pragma unroll
                for (int r = 0; r < 4; ++r) {
                    const int qr = (l >> 4) * 4 + r;
                    px[qr * NT + t] = cxy[n][r];
                    ps[qr * NT + t] = csy[n][r];
                }
            }
        }
        // row sums: lanes {l, l+16, l+32, l+48} share one q-row
        sx += __shfl_xor(sx, 16); sx += __shfl_xor(sx, 32);
        l2 += __shfl_xor(l2, 16); l2 += __shfl_xor(l2, 32);
        sg += __shfl_xor(sg, 16); sg += __shfl_xor(sg, 32);
        if (l < 16) {
            px[400 + l] = sx - 0.69314718056f * l2;   // softplus row-sum partial
            ps[400 + l] = sg;                          // sigma row-sum partial
        }
    } else {
        // A == ones -> every C row = sum_k y[t]; write Sum(y) slot (qt=7)
        const size_t slot7 = ((size_t)(b * 8 + 7) * NKB + chunk) * SLOT;
        float* p7 = ws + WS_P0 + slot7;
        if (l < 16) p7[l] = cxy[0][0];
        if (l < NT - 16) p7[16 + l] = cxy[1][0];
    }
}

__global__ __launch_bounds__(256) void finalize_kernel(
    const float* __restrict__ logits,  // [BS,NQ,NC]
    const int* __restrict__ labels,    // [BS,NT]
    const float* __restrict__ ws,
    float* __restrict__ out)           // [BS,NQ,NT]
{
    __shared__ float s1[256];
    __shared__ float s2[256];
    __shared__ float s3[256];
    __shared__ float s4[256];

    const int row = blockIdx.x;        // b*NQ + q
    const int b = row / NQ, q = row % NQ;
    const int qt = q / 16, qr = q % 16;
    const int tid = threadIdx.x;
    const int t = tid & 31, cg = tid >> 5;     // 8 chunk-groups

    const float* px = ws + WS_P0 + (size_t)(b * 8 + qt) * NKB * SLOT;
    const float* ps = ws + WS_P1 + (size_t)(b * 8 + qt) * NKB * SLOT;
    const float* p7 = ws + WS_P0 + (size_t)(b * 8 + 7) * NKB * SLOT;

    float a1 = 0.f, a2 = 0.f, a3 = 0.f, a4 = 0.f;
    if (t < NT) {
        #pragma unroll 4
        for (int k = 0; k < NKB / 8; ++k) {
            const size_t o = (size_t)(cg + 8 * k) * SLOT;
            a1 += px[o + qr * NT + t];     // xy partial
            a2 += ps[o + qr * NT + t];     // sy partial
            a3 += p7[o + t];               // Sum_y partial
        }
    } else if (t == 25) {
        #pragma unroll 4
        for (int k = 0; k < NKB / 8; ++k)
            a4 += px[(size_t)(cg + 8 * k) * SLOT + 400 + qr];   // softplus row sum
    } else if (t == 26) {
        #pragma unroll 4
        for (int k = 0; k < NKB / 8; ++k)
            a4 += ps[(size_t)(cg + 8 * k) * SLOT + 400 + qr];   // sigma row sum
    }
    s1[tid] = a1;
    s2[tid] = a2;
    s3[tid] = a3;
    s4[tid] = a4;
    __syncthreads();

    if (tid < 64) {
        const float* lg = logits + (size_t)row * NC;
        float v0 = (tid < NC) ? lg[tid] : -1e30f;
        float v1 = (tid + 64 < NC) ? lg[tid + 64] : -1e30f;
        float mx = fmaxf(v0, v1);
        #pragma unroll
        for (int off = 32; off; off >>= 1) mx = fmaxf(mx, __shfl_xor(mx, off, 64));
        float e = ((tid < NC) ? __expf(v0 - mx) : 0.f) +
                  ((tid + 64 < NC) ? __expf(v1 - mx) : 0.f);
        #pragma unroll
        for (int off = 32; off; off >>= 1) e += __shfl_xor(e, off, 64);

        if (tid < NT) {
            float xy = 0.f, sy = 0.f, yt = 0.f, sp = 0.f, sg = 0.f;
            #pragma unroll
            for (int g = 0; g < 8; ++g) {
                xy += s1[g * 32 + tid];
                sy += s2[g * 32 + tid];
                yt += s3[g * 32 + tid];
                sp += s4[g * 32 + 25];
                sg += s4[g * 32 + 26];
            }

            const int lab = labels[b * NT + tid];
            const float prob = __expf(lg[lab] - mx) / e;
            const float inv_p = 1.0f / (float)PIX;
            const float bce = sp * inv_p - xy * inv_p;
            const float dice = 1.0f - 2.0f * sy / (sg + yt + 1e-6f);
            out[(size_t)row * NT + tid] = -prob + bce + dice;
        }
    }
}

extern "C" void kernel_launch(void* const* d_in, const int* in_sizes, int n_in,
                              void* d_out, int out_size, void* d_ws, size_t ws_size,
                              hipStream_t stream) {
    const float* pred_logits = (const float*)d_in[0];
    const float* pred_masks  = (const float*)d_in[1];
    const int*   tgt_labels  = (const int*)d_in[2];
    const float* tgt_masks   = (const float*)d_in[3];
    float* out = (float*)d_out;
    float* ws  = (float*)d_ws;

    // No memset, no atomics: every location finalize reads is unconditionally
    // overwritten by partial_kernel each call.
    partial_kernel<<<BS * 2 * NKB, 256, 0, stream>>>(pred_masks, tgt_masks, ws);
    finalize_kernel<<<BS * NQ, 256, 0, stream>>>(pred_logits, tgt_labels, ws, out);
}